// Round 8
// baseline (145.608 us; speedup 1.0000x reference)
//
#include <hip/hip_runtime.h>

// Ball query (PointNet++ semantics), MI355X / gfx950 — two-phase dense.
// B=8, N=16384, M=1024, K=64, r2=0.04f.
//
// Phase 1 (bq_mask): LANE = CENTROID, POINT = uniform loop index.
//   Each lane holds its centroid {cx,cy,cz,c2} in VGPRs; the point stream
//   {px,py,pz,p2} is wave-uniform (scalar-pipe float4 loads). Each lane
//   accumulates its own hit-bit word (bit i = point ch*64+i) -> NO cross-lane
//   ops in the hot loop (round-7's writelane builtin doesn't exist).
//   ~8 VALU wave-instrs per 64 pairs -> ~14us floor, zero straggler tail.
// Phase 2 (bq_compact): one wave per centroid, first-K set-bit extraction
//   with popc + shfl scan. Ascending point-index order preserved.
//
// CLASSIFICATION ARITHMETIC (verified passing, round 4 — do not change):
//   cp  = fma(cz,pz, fma(cy,py, fl(cx*px)))
//   p2,c2 = strict mul + sequential add (no FMA)
//   d2  = fl( fl(c2+p2) - 2*cp ),  compare <= 0.04f
// d2 = fmaf(-2,cp,t) is bit-identical to fl(t - fl(2*cp)): 2*cp is exact
// (binade shift), so the fma's single rounding equals the sub's rounding.
//
// ws layout (19 MB needed):
//   [0, 128KB)            float4 centArr[8192]   {cx,cy,cz,c2}
//   [128KB, 128KB+2MB)    float4 pointArr[131072]{px,py,pz,p2}
//   [+, +16.78MB)         u64 words[8192][256]   word ch of centroid cid

#define BQ_N 16384
#define BQ_M 1024
#define BQ_B 8
#define BQ_K 64
#define BQ_R2 0.04f

// ---------------- Phase 0: pack points (strict p2) + centroids (strict c2) --
__global__ __launch_bounds__(256) void bq_prep(
    const float* __restrict__ pts, const float* __restrict__ cents,
    float4* __restrict__ pointArr, float4* __restrict__ centArr)
{
    const int t = blockIdx.x * 256 + threadIdx.x;    // 0..131071
    {
        const int b = t >> 14, n = t & (BQ_N - 1);
        const float* p = pts + (size_t)b * 3 * BQ_N;
        const float px = p[n], py = p[BQ_N + n], pz = p[2 * BQ_N + n];
        const float p2 = __fadd_rn(__fadd_rn(__fmul_rn(px, px), __fmul_rn(py, py)),
                                   __fmul_rn(pz, pz));
        pointArr[t] = make_float4(px, py, pz, p2);
    }
    if (t < BQ_B * BQ_M) {
        const int b = t >> 10, m = t & (BQ_M - 1);
        const float* c = cents + (size_t)b * 3 * BQ_M;
        const float cx = c[m], cy = c[BQ_M + m], cz = c[2 * BQ_M + m];
        const float c2 = __fadd_rn(__fadd_rn(__fmul_rn(cx, cx), __fmul_rn(cy, cy)),
                                   __fmul_rn(cz, cz));
        centArr[t] = make_float4(cx, cy, cz, c2);
    }
}

// ---------------- Phase 1: dense hit bitmask, lane = centroid ----------------
// Grid: 1024 blocks x 4 waves. Block -> (b, cgroup of 64 centroids, 4-pgroup
// cluster); wave w -> pgroup = (rem&7)*4+w, covering 512 points (8 chunks).
__global__ __launch_bounds__(256) void bq_mask(
    const float4* __restrict__ pointArr,
    const float4* __restrict__ centArr,
    unsigned long long* __restrict__ words)
{
    const int lane = threadIdx.x & 63;
    const int wid  = threadIdx.x >> 6;
    const int b    = blockIdx.x >> 7;            // 8 batches x 128 blocks
    const int rem  = blockIdx.x & 127;
    const int cg   = rem >> 3;                   // 16 centroid groups of 64
    const int pg   = ((rem & 7) << 2) + wid;     // 32 point groups of 512

    const int cid = (b << 10) + (cg << 6) + lane;
    const float4 cc = centArr[cid];              // coalesced 16B/lane
    const float cx = cc.x, cy = cc.y, cz = cc.z, c2 = cc.w;

    unsigned long long w64[8];

    #pragma unroll
    for (int c = 0; c < 8; ++c) {
        const int ch = (pg << 3) + c;            // chunk of 64 points
        const float4* pb = pointArr + (b << 14) + (ch << 6);
        unsigned wlo = 0, whi = 0;
        #pragma unroll 16
        for (int i = 0; i < 64; ++i) {
            const float4 pp = pb[i];             // wave-uniform -> scalar pipe
            float cp = __fmul_rn(cx, pp.x);
            cp = __fmaf_rn(cy, pp.y, cp);
            cp = __fmaf_rn(cz, pp.z, cp);
            const float t  = __fadd_rn(c2, pp.w);
            const float d2 = __fmaf_rn(-2.0f, cp, t);
            const bool hit = (d2 <= BQ_R2);
            if (i < 32) wlo |= (hit ? 1u : 0u) << i;
            else        whi |= (hit ? 1u : 0u) << (i - 32);
        }
        w64[c] = ((unsigned long long)whi << 32) | wlo;
    }

    // 64B per lane, written as 4x16B stores.
    ulonglong2* dst = (ulonglong2*)(words + (((size_t)cid) << 8) + (pg << 3));
    dst[0] = make_ulonglong2(w64[0], w64[1]);
    dst[1] = make_ulonglong2(w64[2], w64[3]);
    dst[2] = make_ulonglong2(w64[4], w64[5]);
    dst[3] = make_ulonglong2(w64[6], w64[7]);
}

// ---------------- Phase 2: per-centroid first-K compaction ----------------
__global__ __launch_bounds__(256) void bq_compact(
    const unsigned long long* __restrict__ words, int* __restrict__ out)
{
    const int lane = threadIdx.x & 63;
    const int cid  = (blockIdx.x << 2) + (threadIdx.x >> 6);

    const unsigned long long* wp = words + ((size_t)cid << 8) + (lane << 2);
    const unsigned long long w0 = wp[0], w1 = wp[1], w2 = wp[2], w3 = wp[3];

    const int tot = __popcll(w0) + __popcll(w1) + __popcll(w2) + __popcll(w3);

    // Inclusive shfl scan over 64 lanes.
    int pre = tot;
    #pragma unroll
    for (int off = 1; off < 64; off <<= 1) {
        const int n = __shfl_up(pre, off);
        if (lane >= off) pre += n;
    }
    const int total = __shfl(pre, 63);
    const int excl  = pre - tot;

    // First neighbor index (0 if none) — lowest set bit overall.
    int first = 0;
    const unsigned long long nz = __ballot(tot != 0);
    if (nz) {
        const int l0 = __builtin_ctzll(nz);
        int f = 0;
        if (lane == l0) {
            if      (w0) f = (lane << 8)       + __builtin_ctzll(w0);
            else if (w1) f = (lane << 8) + 64  + __builtin_ctzll(w1);
            else if (w2) f = (lane << 8) + 128 + __builtin_ctzll(w2);
            else         f = (lane << 8) + 192 + __builtin_ctzll(w3);
        }
        first = __shfl(f, l0);
    }

    int* o = out + ((size_t)cid << 6);

    int slot = excl;
    if (tot && slot < BQ_K) {
        const unsigned long long wv[4] = {w0, w1, w2, w3};
        #pragma unroll
        for (int j = 0; j < 4; ++j) {
            unsigned long long w = wv[j];
            while (w && slot < BQ_K) {
                o[slot++] = (lane << 8) + (j << 6) + __builtin_ctzll(w);
                w &= w - 1;
            }
        }
    }

    const int cnt = total < BQ_K ? total : BQ_K;
    if (lane >= cnt) o[lane] = first;
}

extern "C" void kernel_launch(void* const* d_in, const int* in_sizes, int n_in,
                              void* d_out, int out_size, void* d_ws, size_t ws_size,
                              hipStream_t stream) {
    const float* pts   = (const float*)d_in[0];   // [8, 3, 16384] f32
    const float* cents = (const float*)d_in[1];   // [8, 3, 1024]  f32
    int* out = (int*)d_out;                       // [8, 1024, 64] int32

    char* ws = (char*)d_ws;
    float4* centArr  = (float4*)ws;                               // 128 KB
    float4* pointArr = (float4*)(ws + (size_t)BQ_B * BQ_M * 16);  // 2 MB
    unsigned long long* words =
        (unsigned long long*)(ws + (size_t)BQ_B * BQ_M * 16
                                 + (size_t)BQ_B * BQ_N * 16);     // 16.78 MB

    bq_prep<<<(BQ_B * BQ_N) / 256, 256, 0, stream>>>(pts, cents, pointArr, centArr);
    bq_mask<<<1024, 256, 0, stream>>>(pointArr, centArr, words);
    bq_compact<<<(BQ_B * BQ_M) / 4, 256, 0, stream>>>(words, out);
}

// Round 9
// 102.696 us; speedup vs baseline: 1.4178x; 1.4178x over previous
//
#include <hip/hip_runtime.h>

// Ball query (PointNet++ semantics), MI355X / gfx950 — dense bitmask, 2 kernels.
// B=8, N=16384, M=1024, K=64, r2=0.04f.
//
// Round-8 lesson: "wave-uniform pointer load -> scalar pipe" does NOT happen
// when the address involves threadIdx-derived values; each point became a
// 64-lane global broadcast load (1 KB of L1 traffic per point per wave) and
// VALU address math -> 83.7us. Fix: stage the point tile in LDS. Same-address
// ds_read is a HW broadcast (free, conflict-less), and SGPR base + constant
// offset means zero per-point address VALU.
//
// bq_mask: block = (batch b, 64-centroid group, 1024-point tile). Lane =
//   centroid (regs {cx,cy,cz,c2}); wave wid classifies tile points
//   [wid*256, +256) read broadcast from LDS -> 4 u64 hit-words per lane.
//   8 VALU per 64 pairs -> ~14us floor across 8192 waves, no tail.
// bq_compact: one wave per centroid, first-K set-bit extraction via
//   popc + shfl scan (verified round 8).
//
// CLASSIFICATION ARITHMETIC (verified passing, rounds 4 & 8 — do not change):
//   cp  = fma(cz,pz, fma(cy,py, fl(cx*px)))
//   p2,c2 = strict mul + sequential add (no FMA)
//   d2  = fmaf(-2, cp, fl(c2+p2))   == fl(fl(c2+p2) - fl(2*cp)) exactly,
//         because 2*cp is exact (binade shift) so fma's one rounding = sub's.
//   compare d2 <= 0.04f
//
// ws: u64 words[8192][256] = 16.78 MB. words[cid][ch] bit i = hit(pt 64ch+i).

#define BQ_N 16384
#define BQ_M 1024
#define BQ_B 8
#define BQ_K 64
#define BQ_R2 0.04f

// ---------------- Phase 1: dense hit bitmask ----------------
__global__ __launch_bounds__(256) void bq_mask(
    const float* __restrict__ pts,
    const float* __restrict__ cents,
    unsigned long long* __restrict__ words)
{
    __shared__ float4 tile[1024];        // 16 KB: {px,py,pz,p2}

    const int tid  = threadIdx.x;
    const int lane = tid & 63;
    const int wid  = __builtin_amdgcn_readfirstlane(tid >> 6);

    const int bi  = blockIdx.x;          // 2048 = 8 batches * 16 cgroups * 16 tiles
    const int b   = bi >> 8;
    const int cg  = (bi >> 4) & 15;      // 64-centroid group
    const int pgc = bi & 15;             // 1024-point tile

    // Centroid per lane, register-resident; strict c2.
    const float* c = cents + (size_t)b * 3 * BQ_M;
    const int m = (cg << 6) + lane;
    const float cx = c[m], cy = c[BQ_M + m], cz = c[2 * BQ_M + m];
    const float c2 = __fadd_rn(__fadd_rn(__fmul_rn(cx, cx), __fmul_rn(cy, cy)),
                               __fmul_rn(cz, cz));

    // Stage 1024 points into LDS with strict p2 (coalesced plane loads).
    const float* p = pts + (size_t)b * 3 * BQ_N;
    const int nbase = pgc << 10;
    #pragma unroll
    for (int j = 0; j < 4; ++j) {
        const int t = (j << 8) + tid;    // tile-local point
        const int n = nbase + t;
        const float px = p[n], py = p[BQ_N + n], pz = p[2 * BQ_N + n];
        const float p2 = __fadd_rn(__fadd_rn(__fmul_rn(px, px), __fmul_rn(py, py)),
                                   __fmul_rn(pz, pz));
        tile[t] = make_float4(px, py, pz, p2);
    }
    __syncthreads();

    // Classify: wave wid handles tile points [wid*256, wid*256+256).
    unsigned long long w64[4];
    #pragma unroll
    for (int ch = 0; ch < 4; ++ch) {
        unsigned lo = 0, hi = 0;
        #pragma unroll
        for (int i = 0; i < 64; ++i) {
            const float4 pp = tile[(wid << 8) + (ch << 6) + i];  // LDS broadcast
            float cp = __fmul_rn(cx, pp.x);
            cp = __fmaf_rn(cy, pp.y, cp);
            cp = __fmaf_rn(cz, pp.z, cp);
            const float t  = __fadd_rn(c2, pp.w);
            const float d2 = __fmaf_rn(-2.0f, cp, t);
            const bool hit = (d2 <= BQ_R2);
            if (i < 32) lo |= (hit ? (1u << i) : 0u);
            else        hi |= (hit ? (1u << (i - 32)) : 0u);
        }
        w64[ch] = ((unsigned long long)hi << 32) | lo;
    }

    // 32 B/lane contiguous: words[cid][pgc*16 + wid*4 .. +3].
    const int cid = (b << 10) + (cg << 6) + lane;
    ulonglong2* dst = (ulonglong2*)(words + (((size_t)cid) << 8)
                                          + (pgc << 4) + (wid << 2));
    dst[0] = make_ulonglong2(w64[0], w64[1]);
    dst[1] = make_ulonglong2(w64[2], w64[3]);
}

// ---------------- Phase 2: per-centroid first-K compaction ----------------
__global__ __launch_bounds__(256) void bq_compact(
    const unsigned long long* __restrict__ words, int* __restrict__ out)
{
    const int lane = threadIdx.x & 63;
    const int cid  = (blockIdx.x << 2) + (threadIdx.x >> 6);

    const unsigned long long* wp = words + ((size_t)cid << 8) + (lane << 2);
    const unsigned long long w0 = wp[0], w1 = wp[1], w2 = wp[2], w3 = wp[3];

    const int tot = __popcll(w0) + __popcll(w1) + __popcll(w2) + __popcll(w3);

    // Inclusive shfl scan over 64 lanes.
    int pre = tot;
    #pragma unroll
    for (int off = 1; off < 64; off <<= 1) {
        const int n = __shfl_up(pre, off);
        if (lane >= off) pre += n;
    }
    const int total = __shfl(pre, 63);
    const int excl  = pre - tot;

    // First neighbor index (0 if none) — lowest set bit overall.
    int first = 0;
    const unsigned long long nz = __ballot(tot != 0);
    if (nz) {
        const int l0 = __builtin_ctzll(nz);
        int f = 0;
        if (lane == l0) {
            if      (w0) f = (lane << 8)       + __builtin_ctzll(w0);
            else if (w1) f = (lane << 8) + 64  + __builtin_ctzll(w1);
            else if (w2) f = (lane << 8) + 128 + __builtin_ctzll(w2);
            else         f = (lane << 8) + 192 + __builtin_ctzll(w3);
        }
        first = __shfl(f, l0);
    }

    int* o = out + ((size_t)cid << 6);

    int slot = excl;
    if (tot && slot < BQ_K) {
        const unsigned long long wv[4] = {w0, w1, w2, w3};
        #pragma unroll
        for (int j = 0; j < 4; ++j) {
            unsigned long long w = wv[j];
            while (w && slot < BQ_K) {
                o[slot++] = (lane << 8) + (j << 6) + __builtin_ctzll(w);
                w &= w - 1;
            }
        }
    }

    const int cnt = total < BQ_K ? total : BQ_K;
    if (lane >= cnt) o[lane] = first;
}

extern "C" void kernel_launch(void* const* d_in, const int* in_sizes, int n_in,
                              void* d_out, int out_size, void* d_ws, size_t ws_size,
                              hipStream_t stream) {
    const float* pts   = (const float*)d_in[0];   // [8, 3, 16384] f32
    const float* cents = (const float*)d_in[1];   // [8, 3, 1024]  f32
    int* out = (int*)d_out;                       // [8, 1024, 64] int32

    unsigned long long* words = (unsigned long long*)d_ws;   // 16.78 MB

    bq_mask<<<2048, 256, 0, stream>>>(pts, cents, words);
    bq_compact<<<(BQ_B * BQ_M) / 4, 256, 0, stream>>>(words, out);
}

// Round 10
// 88.987 us; speedup vs baseline: 1.6363x; 1.1541x over previous
//
#include <hip/hip_runtime.h>

// Ball query (PointNet++ semantics), MI355X / gfx950 — dense bitmask, 2 kernels.
// B=8, N=16384, M=1024, K=64, r2=0.04f (bits 0x3D23D70A).
//
// Round-9 lesson: lane=centroid×1 + LDS broadcast is LDS-ISSUE-bound:
// 2.1M ds_read_b128 (one per wave per point) x ~12cyc/CU ≈ 41us = measured
// 43.7us. Fix: 4 CENTROIDS PER LANE -> each broadcast read feeds 4x the
// pairs (524k reads, ~10us), dropping LDS below the VALU floor (~12us).
// Bit-append via v_cmp + v_addc (1 instr instead of cndmask+or) = 7 VALU/pair.
//
// bq_mask: grid 512 = 8b x 4cg(256 centroids) x 16 tiles(1024 pts);
//   block = 4 waves, wave = 256-pt quarter. Lane holds 4 centroids
//   (cg*256 + q*64 + lane). acc = (acc<<1)|hit over ascending i, then
//   bitreverse32 per 32-pt half -> words[cid][ch] bit i = hit(pt 64ch+i).
// bq_compact: one wave per centroid, first-K set-bit extraction via
//   popc + shfl scan (verified rounds 8-9).
//
// CLASSIFICATION ARITHMETIC (verified passing rounds 4/8/9 — do not change):
//   cp  = fma(cz,pz, fma(cy,py, fl(cx*px)))
//   p2,c2 = strict mul + sequential add (no FMA)
//   d2  = fmaf(-2, cp, fl(c2+p2))  == fl(fl(c2+p2) - fl(2*cp)) exactly
//   hit = d2 <= 0.04f   (asm: v_cmp_ge_f32 vcc, 0x3d23d70a, d2)
//
// ws: u64 words[8192][256] = 16.78 MB.

#define BQ_N 16384
#define BQ_M 1024
#define BQ_B 8
#define BQ_K 64

// ---------------- Phase 1: dense hit bitmask, 4 centroids/lane ----------------
__global__ __launch_bounds__(256) void bq_mask(
    const float* __restrict__ pts,
    const float* __restrict__ cents,
    unsigned long long* __restrict__ words)
{
    __shared__ float4 tile[1024];        // 16 KB: {px,py,pz,p2}

    const int tid  = threadIdx.x;
    const int lane = tid & 63;
    const int wid  = __builtin_amdgcn_readfirstlane(tid >> 6);

    const int bi = blockIdx.x;           // 512 = 8 b * 4 cg * 16 tiles
    const int b  = bi >> 6;
    const int cg = (bi >> 4) & 3;        // 256-centroid group
    const int tl = bi & 15;              // 1024-point tile

    // 4 register-resident centroids per lane; strict c2.
    const float* c = cents + (size_t)b * 3 * BQ_M;
    float cx[4], cy[4], cz[4], c2[4];
    #pragma unroll
    for (int q = 0; q < 4; ++q) {
        const int m = (cg << 8) + (q << 6) + lane;
        cx[q] = c[m]; cy[q] = c[BQ_M + m]; cz[q] = c[2 * BQ_M + m];
        c2[q] = __fadd_rn(__fadd_rn(__fmul_rn(cx[q], cx[q]),
                                    __fmul_rn(cy[q], cy[q])),
                          __fmul_rn(cz[q], cz[q]));
    }

    // Stage 1024 points into LDS with strict p2 (coalesced plane loads).
    const float* p = pts + (size_t)b * 3 * BQ_N;
    const int nbase = tl << 10;
    #pragma unroll
    for (int j = 0; j < 4; ++j) {
        const int t = (j << 8) + tid;
        const int n = nbase + t;
        const float px = p[n], py = p[BQ_N + n], pz = p[2 * BQ_N + n];
        const float p2 = __fadd_rn(__fadd_rn(__fmul_rn(px, px), __fmul_rn(py, py)),
                                   __fmul_rn(pz, pz));
        tile[t] = make_float4(px, py, pz, p2);
    }
    __syncthreads();

    // Wave classifies tile points [wid*256, +256) against its 256 centroids.
    const int pbase = wid << 8;
    unsigned long long w64[4][4];        // [q][chunk]

    #pragma unroll
    for (int ch = 0; ch < 4; ++ch) {
        unsigned lo[4] = {0, 0, 0, 0};
        unsigned hi[4] = {0, 0, 0, 0};

        #pragma unroll 8
        for (int i = 0; i < 32; ++i) {
            const float4 pp = tile[pbase + (ch << 6) + i];   // LDS broadcast
            #pragma unroll
            for (int q = 0; q < 4; ++q) {
                float cp = __fmul_rn(cx[q], pp.x);
                cp = __fmaf_rn(cy[q], pp.y, cp);
                cp = __fmaf_rn(cz[q], pp.z, cp);
                const float t  = __fadd_rn(c2[q], pp.w);
                const float d2 = __fmaf_rn(-2.0f, cp, t);
                // acc = (acc<<1) | (d2 <= 0.04f)  in ONE VALU append:
                asm("v_cmp_ge_f32 vcc, 0x3d23d70a, %1\n\t"
                    "v_addc_co_u32 %0, vcc, %0, %0, vcc"
                    : "+v"(lo[q]) : "v"(d2) : "vcc");
            }
        }
        #pragma unroll 8
        for (int i = 32; i < 64; ++i) {
            const float4 pp = tile[pbase + (ch << 6) + i];   // LDS broadcast
            #pragma unroll
            for (int q = 0; q < 4; ++q) {
                float cp = __fmul_rn(cx[q], pp.x);
                cp = __fmaf_rn(cy[q], pp.y, cp);
                cp = __fmaf_rn(cz[q], pp.z, cp);
                const float t  = __fadd_rn(c2[q], pp.w);
                const float d2 = __fmaf_rn(-2.0f, cp, t);
                asm("v_cmp_ge_f32 vcc, 0x3d23d70a, %1\n\t"
                    "v_addc_co_u32 %0, vcc, %0, %0, vcc"
                    : "+v"(hi[q]) : "v"(d2) : "vcc");
            }
        }
        #pragma unroll
        for (int q = 0; q < 4; ++q) {
            // point i was appended MSB-first: bit(31-i) -> bitreverse fixes.
            w64[q][ch] =
                ((unsigned long long)__builtin_bitreverse32(hi[q]) << 32)
                | __builtin_bitreverse32(lo[q]);
        }
    }

    // Store: region rg covers words [rg*4, rg*4+4) of each centroid.
    const int rg = (tl << 2) + wid;      // 0..63
    #pragma unroll
    for (int q = 0; q < 4; ++q) {
        const int cid = (b << 10) + (cg << 8) + (q << 6) + lane;
        ulonglong2* dst = (ulonglong2*)(words + (((size_t)cid) << 8) + (rg << 2));
        dst[0] = make_ulonglong2(w64[q][0], w64[q][1]);
        dst[1] = make_ulonglong2(w64[q][2], w64[q][3]);
    }
}

// ---------------- Phase 2: per-centroid first-K compaction ----------------
__global__ __launch_bounds__(256) void bq_compact(
    const unsigned long long* __restrict__ words, int* __restrict__ out)
{
    const int lane = threadIdx.x & 63;
    const int cid  = (blockIdx.x << 2) + (threadIdx.x >> 6);

    const unsigned long long* wp = words + ((size_t)cid << 8) + (lane << 2);
    const unsigned long long w0 = wp[0], w1 = wp[1], w2 = wp[2], w3 = wp[3];

    const int tot = __popcll(w0) + __popcll(w1) + __popcll(w2) + __popcll(w3);

    // Inclusive shfl scan over 64 lanes.
    int pre = tot;
    #pragma unroll
    for (int off = 1; off < 64; off <<= 1) {
        const int n = __shfl_up(pre, off);
        if (lane >= off) pre += n;
    }
    const int total = __shfl(pre, 63);
    const int excl  = pre - tot;

    // First neighbor index (0 if none) — lowest set bit overall.
    int first = 0;
    const unsigned long long nz = __ballot(tot != 0);
    if (nz) {
        const int l0 = __builtin_ctzll(nz);
        int f = 0;
        if (lane == l0) {
            if      (w0) f = (lane << 8)       + __builtin_ctzll(w0);
            else if (w1) f = (lane << 8) + 64  + __builtin_ctzll(w1);
            else if (w2) f = (lane << 8) + 128 + __builtin_ctzll(w2);
            else         f = (lane << 8) + 192 + __builtin_ctzll(w3);
        }
        first = __shfl(f, l0);
    }

    int* o = out + ((size_t)cid << 6);

    int slot = excl;
    if (tot && slot < BQ_K) {
        const unsigned long long wv[4] = {w0, w1, w2, w3};
        #pragma unroll
        for (int j = 0; j < 4; ++j) {
            unsigned long long w = wv[j];
            while (w && slot < BQ_K) {
                o[slot++] = (lane << 8) + (j << 6) + __builtin_ctzll(w);
                w &= w - 1;
            }
        }
    }

    const int cnt = total < BQ_K ? total : BQ_K;
    if (lane >= cnt) o[lane] = first;
}

extern "C" void kernel_launch(void* const* d_in, const int* in_sizes, int n_in,
                              void* d_out, int out_size, void* d_ws, size_t ws_size,
                              hipStream_t stream) {
    const float* pts   = (const float*)d_in[0];   // [8, 3, 16384] f32
    const float* cents = (const float*)d_in[1];   // [8, 3, 1024]  f32
    int* out = (int*)d_out;                       // [8, 1024, 64] int32

    unsigned long long* words = (unsigned long long*)d_ws;   // 16.78 MB

    bq_mask<<<512, 256, 0, stream>>>(pts, cents, words);
    bq_compact<<<(BQ_B * BQ_M) / 4, 256, 0, stream>>>(words, out);
}